// Round 9
// baseline (228.103 us; speedup 1.0000x reference)
//
#include <hip/hip_runtime.h>
#include <hip/hip_bf16.h>

// MEASUREMENT ROUND: each kernel body repeated (REP_*) with identical output,
// so every kernel's duration/counters clear the ~43us fillBuffer floor and
// appear in the rocprof top-5.  True per-kernel time = dur_us / REP.
// Also fixes gemm1's inverted per-wave-class vmcnt (latent race).

#define REP_CONVERT 8
#define REP_G1 4
#define REP_ATTN 12
#define REP_G2 6

typedef __bf16 bf16x8_t __attribute__((ext_vector_type(8)));
typedef unsigned short u16x8_t __attribute__((ext_vector_type(8)));
typedef float f32x4_t __attribute__((ext_vector_type(4)));

__device__ __forceinline__ void load_lds16(const void* g, void* l) {
    __builtin_amdgcn_global_load_lds(
        (__attribute__((address_space(1))) void*)(g),
        (__attribute__((address_space(3))) void*)(l),
        16, 0, 0);
}

// ---------------- fp32 -> bf16 conversion (x, Wqkv, Wproj fused) -------------
__global__ __launch_bounds__(256) void convert_all(
    const float* __restrict__ x, const float* __restrict__ wqkv,
    const float* __restrict__ wproj,
    __hip_bfloat16* __restrict__ xb, __hip_bfloat16* __restrict__ wqkvb,
    __hip_bfloat16* __restrict__ wprojb)
{
    const size_t t = (size_t)blockIdx.x * 256 + threadIdx.x;
    size_t i = t * 8;
    const float* src;
    __hip_bfloat16* dst;
    if (i < 4194304) {
        src = x; dst = xb;
    } else if (i < 4194304 + 3145728) {
        src = wqkv; dst = wqkvb; i -= 4194304;
    } else {
        src = wproj; dst = wprojb; i -= 4194304 + 3145728;
    }
    for (int rep = 0; rep < REP_CONVERT; ++rep) {
        float4 v0 = *reinterpret_cast<const float4*>(src + i);
        float4 v1 = *reinterpret_cast<const float4*>(src + i + 4);
        union { u16x8_t v; __hip_bfloat16 h[8]; } u;
        u.h[0] = __float2bfloat16(v0.x); u.h[1] = __float2bfloat16(v0.y);
        u.h[2] = __float2bfloat16(v0.z); u.h[3] = __float2bfloat16(v0.w);
        u.h[4] = __float2bfloat16(v1.x); u.h[5] = __float2bfloat16(v1.y);
        u.h[6] = __float2bfloat16(v1.z); u.h[7] = __float2bfloat16(v1.w);
        *reinterpret_cast<u16x8_t*>(dst + i) = u.v;
        asm volatile("" ::: "memory");
    }
}

// ---------------- GEMM1: qkv = xb @ WqkvT, bf16 out --------------------------
__global__ __launch_bounds__(512, 2) void gemm1_qkv256(
    const __hip_bfloat16* __restrict__ A,   // [4096,1024]
    const __hip_bfloat16* __restrict__ B,   // [3072,1024]
    __hip_bfloat16* __restrict__ C)         // [4096,3072]
{
    __shared__ __align__(16) char smem[114688];   // 4 slots x (16KB A + 12KB B)
    const int tid = threadIdx.x;

    const int orig = blockIdx.y * 16 + blockIdx.x;
    const int xcd = orig & 7, slot = orig >> 3;
    const int hi = slot >> 4;
    const int s  = xcd * 2 + hi;
    const int w  = slot & 15;
    const int m0 = ((s & 3) * 4 + (w & 3)) * 256;
    const int n0 = ((s >> 2) * 4 + (w >> 2)) * 192;

    const int wave = tid >> 6, lane = tid & 63;
    const int wr = wave >> 2, wc = wave & 3;
    const int lr = lane & 15, kg = lane >> 4;
    const int K = 1024, Nn = 3072;

    const int qa0 = tid, qa1 = tid + 512;
    const int qb0 = tid, qb1 = tid + 256;
    const int ra0 = qa0 >> 2, sa0 = ((qa0 & 3) ^ ((ra0 >> 1) & 3)) * 16;
    const int ra1 = qa1 >> 2, sa1 = ((qa1 & 3) ^ ((ra1 >> 1) & 3)) * 16;
    const int rb0 = qb0 >> 2, sb0 = ((qb0 & 3) ^ ((rb0 >> 1) & 3)) * 16;
    const int rb1 = qb1 >> 2, sb1 = ((qb1 & 3) ^ ((rb1 >> 1) & 3)) * 16;
    const char* Asrc0 = (const char*)(A + (size_t)(m0 + ra0) * K) + sa0;
    const char* Asrc1 = (const char*)(A + (size_t)(m0 + ra1) * K) + sa1;
    const char* Bsrc0 = (const char*)(B + (size_t)(n0 + rb0) * K) + sb0;
    const char* Bsrc1 = (const char*)(B + (size_t)(n0 + rb1) * K) + sb1;
    const bool bextra = (tid >= 256);             // waves 4-7: 2A+2B=4/tile, else 3

#define STAGE_A(t) { const int sb_ = ((t) & 3) * 28672; const int ko_ = (t) * 64; \
    load_lds16(Asrc0 + ko_, smem + sb_ + qa0 * 16);                                \
    load_lds16(Asrc1 + ko_, smem + sb_ + qa1 * 16); }
#define STAGE_B(t) { const int sb_ = ((t) & 3) * 28672; const int ko_ = (t) * 64; \
    load_lds16(Bsrc0 + ko_, smem + sb_ + 16384 + qb0 * 16);                        \
    if (bextra) load_lds16(Bsrc1 + ko_, smem + sb_ + 16384 + qb1 * 16); }

    f32x4_t acc[8][3];
    const int rsw = ((kg ^ ((lr >> 1) & 3)) * 16);
    const int arow = wr * 128 + lr;
    const int brow = wc * 48 + lr;

    for (int rep = 0; rep < REP_G1; ++rep) {
        __syncthreads();
#pragma unroll
        for (int mi = 0; mi < 8; ++mi)
#pragma unroll
            for (int ni = 0; ni < 3; ++ni) acc[mi][ni] = (f32x4_t){0.f, 0.f, 0.f, 0.f};

        STAGE_A(0); STAGE_B(0);
        STAGE_A(1); STAGE_B(1);
        // corrected: 3-load waves wait to <=3, 4-load waves to <=4 (tile 0 landed)
        if (!bextra) { asm volatile("s_waitcnt vmcnt(3)" ::: "memory"); }
        else         { asm volatile("s_waitcnt vmcnt(4)" ::: "memory"); }
        __builtin_amdgcn_s_barrier();

        for (int t = 0; t < 32; ++t) {
            const int sb_ = (t & 3) * 28672;
            bf16x8_t a_[8], b_[3];
#pragma unroll
            for (int mi = 0; mi < 4; ++mi)
                a_[mi] = *(const bf16x8_t*)(smem + sb_ + (arow + mi * 16) * 64 + rsw);
#pragma unroll
            for (int ni = 0; ni < 3; ++ni)
                b_[ni] = *(const bf16x8_t*)(smem + sb_ + 16384 + (brow + ni * 16) * 64 + rsw);
            if (t < 30) STAGE_A(t + 2);
            __builtin_amdgcn_s_barrier();
            __builtin_amdgcn_s_setprio(1);
#pragma unroll
            for (int mi = 0; mi < 4; ++mi)
#pragma unroll
                for (int ni = 0; ni < 3; ++ni)
                    acc[mi][ni] = __builtin_amdgcn_mfma_f32_16x16x32_bf16(
                        a_[mi], b_[ni], acc[mi][ni], 0, 0, 0);
            __builtin_amdgcn_s_setprio(0);
            __builtin_amdgcn_s_barrier();
#pragma unroll
            for (int mi = 4; mi < 8; ++mi)
                a_[mi] = *(const bf16x8_t*)(smem + sb_ + (arow + mi * 16) * 64 + rsw);
            if (t < 30) {
                STAGE_B(t + 2);
                // corrected: guarantee tile t+1 fully landed before next phase-A reads
                if (!bextra) { asm volatile("s_waitcnt vmcnt(3)" ::: "memory"); }
                else         { asm volatile("s_waitcnt vmcnt(4)" ::: "memory"); }
            } else {
                asm volatile("s_waitcnt vmcnt(0)" ::: "memory");
            }
            __builtin_amdgcn_s_barrier();
            __builtin_amdgcn_s_setprio(1);
#pragma unroll
            for (int mi = 4; mi < 8; ++mi)
#pragma unroll
                for (int ni = 0; ni < 3; ++ni)
                    acc[mi][ni] = __builtin_amdgcn_mfma_f32_16x16x32_bf16(
                        a_[mi], b_[ni], acc[mi][ni], 0, 0, 0);
            __builtin_amdgcn_s_setprio(0);
            __builtin_amdgcn_s_barrier();
        }
        asm volatile("" ::: "memory");
    }
#undef STAGE_A
#undef STAGE_B

    __syncthreads();
    __hip_bfloat16* cl = (__hip_bfloat16*)smem;
#pragma unroll
    for (int mi = 0; mi < 8; ++mi)
#pragma unroll
        for (int ni = 0; ni < 3; ++ni)
#pragma unroll
            for (int r = 0; r < 4; ++r)
                cl[(wr * 128 + mi * 16 + kg * 4 + r) * 200 + wc * 48 + ni * 16 + lr] =
                    __float2bfloat16(acc[mi][ni][r]);
    __syncthreads();
#pragma unroll
    for (int c = 0; c < 12; ++c) {
        const int id = tid + c * 512;
        const int row = id / 24, cc = id - row * 24;
        f32x4_t v = *(const f32x4_t*)(smem + row * 400 + cc * 16);
        *(f32x4_t*)((char*)C + ((size_t)(m0 + row) * Nn + n0) * 2 + cc * 16) = v;
    }
}

// ---------------- GEMM2: out = ctx @ WprojT + bias, fp32 out -----------------
__global__ __launch_bounds__(512, 2) void gemm2_proj128(
    const __hip_bfloat16* __restrict__ A,
    const __hip_bfloat16* __restrict__ B,
    float* __restrict__ C,
    const float* __restrict__ bias)
{
    __shared__ __align__(16) char smem[65536];
    const int tid = threadIdx.x;
    const int orig = blockIdx.y * 8 + blockIdx.x;
    const int wgid = (orig & 7) * 32 + (orig >> 3);
    const int m0 = (wgid >> 3) * 128, n0 = (wgid & 7) * 128;

    const int wave = tid >> 6, lane = tid & 63;
    const int wr = wave >> 2, wc = wave & 3;
    const int lr = lane & 15, kg = lane >> 4;
    const int K = 1024, Nn = 1024;

    const int q = tid;
    const int row = q >> 2, sl = ((q & 3) ^ ((row >> 1) & 3)) * 16;
    const char* Asrc = (const char*)(A + (size_t)(m0 + row) * K) + sl;
    const char* Bsrc = (const char*)(B + (size_t)(n0 + row) * K) + sl;

#define STAGE2(t) { const int sb_ = ((t) & 3) * 16384; const int ko_ = (t) * 64; \
    load_lds16(Asrc + ko_, smem + sb_ + q * 16);                                  \
    load_lds16(Bsrc + ko_, smem + sb_ + 8192 + q * 16); }

    f32x4_t acc[4][2];
    const int rsw = ((kg ^ ((lr >> 1) & 3)) * 16);
    const int arow = wr * 64 + lr;
    const int brow = wc * 32 + lr;

    for (int rep = 0; rep < REP_G2; ++rep) {
        __syncthreads();
#pragma unroll
        for (int mi = 0; mi < 4; ++mi)
#pragma unroll
            for (int ni = 0; ni < 2; ++ni) acc[mi][ni] = (f32x4_t){0.f, 0.f, 0.f, 0.f};

        STAGE2(0); STAGE2(1);
        asm volatile("s_waitcnt vmcnt(2)" ::: "memory");
        __builtin_amdgcn_s_barrier();

        for (int t = 0; t < 32; ++t) {
            const int sb_ = (t & 3) * 16384;
            if (t < 30) {
                STAGE2(t + 2);
                asm volatile("s_waitcnt vmcnt(4)" ::: "memory");  // drains tile t (oldest)
            } else if (t == 30) {
                asm volatile("s_waitcnt vmcnt(2)" ::: "memory");
            } else {
                asm volatile("s_waitcnt vmcnt(0)" ::: "memory");
            }
            __builtin_amdgcn_s_barrier();
            bf16x8_t a_[4], b_[2];
#pragma unroll
            for (int mi = 0; mi < 4; ++mi)
                a_[mi] = *(const bf16x8_t*)(smem + sb_ + (arow + mi * 16) * 64 + rsw);
#pragma unroll
            for (int ni = 0; ni < 2; ++ni)
                b_[ni] = *(const bf16x8_t*)(smem + sb_ + 8192 + (brow + ni * 16) * 64 + rsw);
            __builtin_amdgcn_s_setprio(1);
#pragma unroll
            for (int mi = 0; mi < 4; ++mi)
#pragma unroll
                for (int ni = 0; ni < 2; ++ni)
                    acc[mi][ni] = __builtin_amdgcn_mfma_f32_16x16x32_bf16(
                        a_[mi], b_[ni], acc[mi][ni], 0, 0, 0);
            __builtin_amdgcn_s_setprio(0);
            __builtin_amdgcn_s_barrier();
        }
        asm volatile("" ::: "memory");
    }
#undef STAGE2

    __syncthreads();
    float* cf = (float*)smem;
#pragma unroll
    for (int p = 0; p < 2; ++p) {
        if (p) __syncthreads();
        if (wr == p) {
#pragma unroll
            for (int mi = 0; mi < 4; ++mi)
#pragma unroll
                for (int ni = 0; ni < 2; ++ni) {
                    const int scol = wc * 32 + ni * 16 + lr;
#pragma unroll
                    for (int r = 0; r < 4; ++r)
                        cf[(mi * 16 + kg * 4 + r) * 132 + scol] = acc[mi][ni][r];
                }
        }
        __syncthreads();
#pragma unroll
        for (int cc = 0; cc < 4; ++cc) {
            const int chunk = tid + cc * 512;
            const int srow = chunk >> 5;
            const int sc = (chunk & 31) * 4;
            f32x4_t v = *(const f32x4_t*)(smem + srow * 528 + sc * 4);
            const f32x4_t bv = *(const f32x4_t*)(bias + n0 + sc);
            v += bv;
            *(f32x4_t*)(C + (size_t)(m0 + p * 64 + srow) * Nn + n0 + sc) = v;
        }
    }
}

// ---------------- banded MFMA attention, block-shared K/V --------------------
__global__ __launch_bounds__(256) void attn_band_mfma(
    const __hip_bfloat16* __restrict__ qkv,
    __hip_bfloat16* __restrict__ ctx,
    const int* __restrict__ epoch_ptr)
{
    __shared__ __align__(16) __hip_bfloat16 K_lds[128 * 64];
    __shared__ __align__(16) __hip_bfloat16 V_lds[64 * 136];
    __shared__ __hip_bfloat16 P_lds[4][16 * 40];

    const int tid = threadIdx.x;
    const int wave = tid >> 6, lane = tid & 63;
    const int lr = lane & 15, kg = lane >> 4;

    const int bid = blockIdx.x;
    const int tg = bid & 15;
    const int bh = bid >> 4;
    const int h = bh & 15, b = bh >> 4;
    const int base = tg * 64;
    const int i0 = base + wave * 16;

    const int e = *epoch_ptr;
    int w;
    if      (e < 20) w = 6;
    else if (e < 30) w = 8;
    else if (e < 40) w = 10;
    else if (e < 50) w = 12;
    else             w = 1023;

    const size_t rowb = (size_t)b * 1024;
    const int hq = h * 192;

    float m[4], l[4];
    f32x4_t o[4];

    for (int rep = 0; rep < REP_ATTN; ++rep) {
        if (rep) __syncthreads();   // protect LDS from re-staging while in use
#pragma unroll
        for (int it = 0; it < 4; ++it) {
            const int q = tid + it * 256;
            const int row = q >> 3, s = q & 7;
            const int c = s ^ (row & 7);
            int gk = base - 32 + row;
            gk = gk < 0 ? 0 : (gk > 1023 ? 1023 : gk);
            load_lds16(qkv + (rowb + gk) * 3072 + hq + 64 + c * 8,
                       (char*)K_lds + q * 16);
        }
        {
            const int pr = tid & 63, dg = tid >> 6;
            int gk0 = base - 32 + 2 * pr, gk1 = gk0 + 1;
            gk0 = gk0 < 0 ? 0 : (gk0 > 1023 ? 1023 : gk0);
            gk1 = gk1 < 0 ? 0 : (gk1 > 1023 ? 1023 : gk1);
            const __hip_bfloat16* v0 = qkv + (rowb + gk0) * 3072 + hq + 128 + dg * 16;
            const __hip_bfloat16* v1 = qkv + (rowb + gk1) * 3072 + hq + 128 + dg * 16;
            u16x8_t a0 = *(const u16x8_t*)v0, b0 = *(const u16x8_t*)(v0 + 8);
            u16x8_t a1 = *(const u16x8_t*)v1, b1 = *(const u16x8_t*)(v1 + 8);
#pragma unroll
            for (int c2 = 0; c2 < 8; ++c2) {
                *(unsigned int*)&V_lds[(dg * 16 + c2) * 136 + 2 * pr] =
                    (unsigned int)a0[c2] | ((unsigned int)a1[c2] << 16);
                *(unsigned int*)&V_lds[(dg * 16 + 8 + c2) * 136 + 2 * pr] =
                    (unsigned int)b0[c2] | ((unsigned int)b1[c2] << 16);
            }
        }

        bf16x8_t aq[2];
#pragma unroll
        for (int ks = 0; ks < 2; ++ks)
            aq[ks] = *(const bf16x8_t*)(qkv + (rowb + i0 + lr) * 3072 + hq + ks * 32 + kg * 8);

        __syncthreads();

#pragma unroll
        for (int r = 0; r < 4; ++r) { m[r] = -1e30f; l[r] = 0.f; }
#pragma unroll
        for (int ni = 0; ni < 4; ++ni) o[ni] = (f32x4_t){0.f, 0.f, 0.f, 0.f};

        int jlo = i0 - w;      if (jlo < 0) jlo = 0;
        int jhi = i0 + 15 + w; if (jhi > 1023) jhi = 1023;
        const int t0 = (base >> 5) - 1;

        for (int p = (jlo >> 5); p <= (jhi >> 5); ++p) {
            const int kb = p * 32;
            const int tl = p - t0;

            f32x4_t s2[2] = {};
#pragma unroll
            for (int t = 0; t < 2; ++t)
#pragma unroll
                for (int ks = 0; ks < 2; ++ks) {
                    const int lkr = tl * 32 + t * 16 + lr;
                    bf16x8_t bk = *(const bf16x8_t*)(
                        (char*)K_lds + lkr * 128 + (((ks * 4 + kg) ^ (lr & 7)) * 16));
                    s2[t] = __builtin_amdgcn_mfma_f32_16x16x32_bf16(aq[ks], bk, s2[t], 0, 0, 0);
                }

            float sv[2][4];
#pragma unroll
            for (int t = 0; t < 2; ++t)
#pragma unroll
                for (int r = 0; r < 4; ++r) {
                    const int qi = i0 + kg * 4 + r;
                    const int j  = kb + t * 16 + lr;
                    int d = qi - j; if (d < 0) d = -d;
                    sv[t][r] = (d <= w) ? s2[t][r] * 0.125f : -1e30f;
                }

            float tm[4];
#pragma unroll
            for (int r = 0; r < 4; ++r) tm[r] = fmaxf(sv[0][r], sv[1][r]);
#pragma unroll
            for (int msk = 1; msk < 16; msk <<= 1)
#pragma unroll
                for (int r = 0; r < 4; ++r) tm[r] = fmaxf(tm[r], __shfl_xor(tm[r], msk));

            float sc[4], ps[4], pvv[2][4];
#pragma unroll
            for (int r = 0; r < 4; ++r) {
                const float mn = fmaxf(m[r], tm[r]);
                sc[r] = __expf(m[r] - mn);
                pvv[0][r] = __expf(sv[0][r] - mn);
                pvv[1][r] = __expf(sv[1][r] - mn);
                ps[r] = pvv[0][r] + pvv[1][r];
                m[r] = mn;
            }
#pragma unroll
            for (int msk = 1; msk < 16; msk <<= 1)
#pragma unroll
                for (int r = 0; r < 4; ++r) ps[r] += __shfl_xor(ps[r], msk);
#pragma unroll
            for (int r = 0; r < 4; ++r) l[r] = l[r] * sc[r] + ps[r];
#pragma unroll
            for (int ni = 0; ni < 4; ++ni)
#pragma unroll
                for (int r = 0; r < 4; ++r) o[ni][r] *= sc[r];

#pragma unroll
            for (int t = 0; t < 2; ++t)
#pragma unroll
                for (int r = 0; r < 4; ++r)
                    P_lds[wave][(kg * 4 + r) * 40 + t * 16 + lr] =
                        __float2bfloat16(pvv[t][r]);

            bf16x8_t ap = *(const bf16x8_t*)&P_lds[wave][lr * 40 + kg * 8];
#pragma unroll
            for (int ni = 0; ni < 4; ++ni) {
                bf16x8_t bv = *(const bf16x8_t*)&V_lds[(ni * 16 + lr) * 136 + tl * 32 + kg * 8];
                o[ni] = __builtin_amdgcn_mfma_f32_16x16x32_bf16(ap, bv, o[ni], 0, 0, 0);
            }
        }
        asm volatile("" ::: "memory");
    }

#pragma unroll
    for (int ni = 0; ni < 4; ++ni)
#pragma unroll
        for (int r = 0; r < 4; ++r)
            ctx[(rowb + i0 + kg * 4 + r) * 1024 + h * 64 + ni * 16 + lr] =
                __float2bfloat16(o[ni][r] / l[r]);
}

// ---------------- launch -----------------------------------------------------
extern "C" void kernel_launch(void* const* d_in, const int* in_sizes, int n_in,
                              void* d_out, int out_size, void* d_ws, size_t ws_size,
                              hipStream_t stream)
{
    const float* x     = (const float*)d_in[0];
    const float* Wqkv  = (const float*)d_in[1];
    const float* Wproj = (const float*)d_in[2];
    const float* bproj = (const float*)d_in[3];
    const int*   epoch = (const int*)d_in[4];

    char* ws = (char*)d_ws;
    __hip_bfloat16* xb     = (__hip_bfloat16*)(ws);
    __hip_bfloat16* wqkvb  = (__hip_bfloat16*)(ws + 8388608);
    __hip_bfloat16* wprojb = (__hip_bfloat16*)(ws + 8388608 + 6291456);
    __hip_bfloat16* qkvb   = (__hip_bfloat16*)(ws + 16777216);
    __hip_bfloat16* ctxb   = (__hip_bfloat16*)(ws + 16777216 + 25165824);

    convert_all<<<4096, 256, 0, stream>>>(x, Wqkv, Wproj, xb, wqkvb, wprojb);

    gemm1_qkv256<<<dim3(16, 16), 512, 0, stream>>>(xb, wqkvb, qkvb);

    attn_band_mfma<<<1024, 256, 0, stream>>>(qkvb, ctxb, epoch);

    gemm2_proj128<<<dim3(8, 32), 512, 0, stream>>>(
        ctxb, wprojb, (float*)d_out, bproj);
}

// Round 10
// 67.938 us; speedup vs baseline: 3.3575x; 3.3575x over previous
//
#include <hip/hip_runtime.h>
#include <hip/hip_bf16.h>

// Problem: B=4, N=1024, C=1024, H=16, D=64.  epoch=25 -> band window w=8.
// 3 dispatches (was 4): fp32->bf16 conversion folded into GEMM staging.
//   gemm1: qkv = bf16(x) @ bf16(Wqkv)^T   (reads fp32, reg-staged cvt)
//   attn:  banded MFMA attention, block-shared K/V
//   gemm2: out = ctx @ bf16(Wproj)^T + bias (fp32 out)
// Rationale (R9 measurement): ~8us launch overhead per dispatch; kernels
// themselves sum to only ~35-45us of the 73.6us wall.

typedef __bf16 bf16x8_t __attribute__((ext_vector_type(8)));
typedef unsigned short u16x8_t __attribute__((ext_vector_type(8)));
typedef float f32x4_t __attribute__((ext_vector_type(4)));

__device__ __forceinline__ void load_lds16(const void* g, void* l) {
    __builtin_amdgcn_global_load_lds(
        (__attribute__((address_space(1))) void*)(g),
        (__attribute__((address_space(3))) void*)(l),
        16, 0, 0);
}

__device__ __forceinline__ u16x8_t cvt8(float4 u, float4 v) {
    union { u16x8_t p; __hip_bfloat16 h[8]; } w;
    w.h[0] = __float2bfloat16(u.x); w.h[1] = __float2bfloat16(u.y);
    w.h[2] = __float2bfloat16(u.z); w.h[3] = __float2bfloat16(u.w);
    w.h[4] = __float2bfloat16(v.x); w.h[5] = __float2bfloat16(v.y);
    w.h[6] = __float2bfloat16(v.z); w.h[7] = __float2bfloat16(v.w);
    return w.p;
}

// ---------------- GEMM1: qkv = x @ WqkvT (fp32 in, bf16 out) -----------------
// 256x192 tile, grid 16x16 = 256 blocks = 1/CU.  8 waves (2M x 4N, 128x48).
// BK=32, 4-slot LDS rotation.  Reg-staged fp32->bf16: loads for tile t+3
// issued at iter t (stay in flight across barriers -- reg deps, no vmcnt(0)),
// ds_writes for tile t+2 at iter t.  One barrier per K-tile.
__global__ __launch_bounds__(512, 2) void gemm1_qkv(
    const float* __restrict__ A,    // x [4096,1024] fp32
    const float* __restrict__ B,    // Wqkv [3072,1024] fp32
    __hip_bfloat16* __restrict__ C) // [4096,3072]
{
    __shared__ __align__(16) char smem[114688];   // 4 slots x (16KB A + 12KB B)
    const int tid = threadIdx.x;

    // XCD-chunked 4x4 super-tiles; bijective: 256 = 8 xcd * 2 * 16.
    const int orig = blockIdx.y * 16 + blockIdx.x;
    const int xcd = orig & 7, slot = orig >> 3;
    const int hi = slot >> 4;
    const int s  = xcd * 2 + hi;
    const int w  = slot & 15;
    const int m0 = ((s & 3) * 4 + (w & 3)) * 256;
    const int n0 = ((s >> 2) * 4 + (w >> 2)) * 192;

    const int wave = tid >> 6, lane = tid & 63;
    const int wr = wave >> 2, wc = wave & 3;
    const int lr = lane & 15, kg = lane >> 4;
    const int K = 1024, Nn = 3072;

    // A tile: 1024 chunks of 8 bf16 (2/thread); B tile: 768 (1 or 2/thread).
    const int qa0 = tid, qa1 = tid + 512;
    const int qb0 = tid, qb1 = tid + 256;
    const int ra0 = qa0 >> 2, ca0 = ((qa0 & 3) ^ ((ra0 >> 1) & 3)) * 8;
    const int ra1 = qa1 >> 2, ca1 = ((qa1 & 3) ^ ((ra1 >> 1) & 3)) * 8;
    const int rb0 = qb0 >> 2, cb0 = ((qb0 & 3) ^ ((rb0 >> 1) & 3)) * 8;
    const int rb1 = qb1 >> 2, cb1 = ((qb1 & 3) ^ ((rb1 >> 1) & 3)) * 8;
    const float* Ap0 = A + (size_t)(m0 + ra0) * K + ca0;
    const float* Ap1 = A + (size_t)(m0 + ra1) * K + ca1;
    const float* Bp0 = B + (size_t)(n0 + rb0) * K + cb0;
    const float* Bp1 = B + (size_t)(n0 + rb1) * K + cb1;
    const bool bextra = (tid >= 256);   // wave-uniform

    float4 a00 = {}, a01 = {}, a10 = {}, a11 = {};
    float4 b00 = {}, b01 = {}, b10 = {}, b11 = {};

#define LOADR(t) { const int ko_ = (t) * 32;                                   \
    a00 = *(const float4*)(Ap0 + ko_); a01 = *(const float4*)(Ap0 + ko_ + 4);  \
    a10 = *(const float4*)(Ap1 + ko_); a11 = *(const float4*)(Ap1 + ko_ + 4);  \
    b00 = *(const float4*)(Bp0 + ko_); b01 = *(const float4*)(Bp0 + ko_ + 4);  \
    if (bextra) { b10 = *(const float4*)(Bp1 + ko_);                           \
                  b11 = *(const float4*)(Bp1 + ko_ + 4); } }
#define WRITE(t) { char* d_ = smem + ((t) & 3) * 28672;                        \
    *(u16x8_t*)(d_ + qa0 * 16) = cvt8(a00, a01);                               \
    *(u16x8_t*)(d_ + qa1 * 16) = cvt8(a10, a11);                               \
    *(u16x8_t*)(d_ + 16384 + qb0 * 16) = cvt8(b00, b01);                       \
    if (bextra) *(u16x8_t*)(d_ + 16384 + qb1 * 16) = cvt8(b10, b11); }

    f32x4_t acc[8][3] = {};
    const int rsw = ((kg ^ ((lr >> 1) & 3)) * 16);
    const int arow = wr * 128 + lr;
    const int brow = wc * 48 + lr;

    LOADR(0); WRITE(0);
    LOADR(1); WRITE(1);
    LOADR(2);                 // in flight across the barrier (reg dest)
    __syncthreads();

    for (int t = 0; t < 32; ++t) {
        const int sb_ = (t & 3) * 28672;
        bf16x8_t a_[8], b_[3];
#pragma unroll
        for (int mi = 0; mi < 8; ++mi)
            a_[mi] = *(const bf16x8_t*)(smem + sb_ + (arow + mi * 16) * 64 + rsw);
#pragma unroll
        for (int ni = 0; ni < 3; ++ni)
            b_[ni] = *(const bf16x8_t*)(smem + sb_ + 16384 + (brow + ni * 16) * 64 + rsw);
        if (t < 30) WRITE(t + 2);   // slot (t+2)&3: nobody reads it this region
        if (t < 29) LOADR(t + 3);
        __builtin_amdgcn_s_setprio(1);
#pragma unroll
        for (int mi = 0; mi < 8; ++mi)
#pragma unroll
            for (int ni = 0; ni < 3; ++ni)
                acc[mi][ni] = __builtin_amdgcn_mfma_f32_16x16x32_bf16(
                    a_[mi], b_[ni], acc[mi][ni], 0, 0, 0);
        __builtin_amdgcn_s_setprio(0);
        __syncthreads();
    }
#undef LOADR
#undef WRITE

    // epilogue via LDS [256][200] bf16 (400B rows), 16B coalesced stores
    __hip_bfloat16* cl = (__hip_bfloat16*)smem;
#pragma unroll
    for (int mi = 0; mi < 8; ++mi)
#pragma unroll
        for (int ni = 0; ni < 3; ++ni)
#pragma unroll
            for (int r = 0; r < 4; ++r)
                cl[(wr * 128 + mi * 16 + kg * 4 + r) * 200 + wc * 48 + ni * 16 + lr] =
                    __float2bfloat16(acc[mi][ni][r]);
    __syncthreads();
#pragma unroll
    for (int c = 0; c < 12; ++c) {
        const int id = tid + c * 512;        // 6144 = 256 rows x 24 chunks
        const int row = id / 24, cc = id - row * 24;
        f32x4_t v = *(const f32x4_t*)(smem + row * 400 + cc * 16);
        *(f32x4_t*)((char*)C + ((size_t)(m0 + row) * Nn + n0) * 2 + cc * 16) = v;
    }
}

// ---------------- GEMM2: out = ctx @ WprojT + bias (fp32 out) ----------------
// 128x128 tile, 256 blocks = 1/CU, 8 waves (2M x 4N, 64x32).  Reg-staged:
// ctx bf16 pass-through, Wproj fp32->bf16 cvt.  Same rotation as gemm1.
__global__ __launch_bounds__(512, 2) void gemm2_proj(
    const __hip_bfloat16* __restrict__ A,   // ctx [4096,1024] bf16
    const float* __restrict__ B,            // Wproj [1024,1024] fp32
    float* __restrict__ C,                  // [4096,1024]
    const float* __restrict__ bias)
{
    __shared__ __align__(16) char smem[65536];   // 4 slots x (8KB A + 8KB B)
    const int tid = threadIdx.x;
    const int orig = blockIdx.y * 8 + blockIdx.x;
    const int wgid = (orig & 7) * 32 + (orig >> 3);   // bijective, 256%8==0
    const int m0 = (wgid >> 3) * 128, n0 = (wgid & 7) * 128;

    const int wave = tid >> 6, lane = tid & 63;
    const int wr = wave >> 2, wc = wave & 3;
    const int lr = lane & 15, kg = lane >> 4;
    const int K = 1024, Nn = 1024;

    const int q = tid;
    const int row = q >> 2, cw = ((q & 3) ^ ((row >> 1) & 3)) * 8;
    const __hip_bfloat16* Ap = A + (size_t)(m0 + row) * K + cw;
    const float*          Bp = B + (size_t)(n0 + row) * K + cw;

    float4 av = {}, bv0 = {}, bv1 = {};

#define LOADR2(t) { const int ko_ = (t) * 32;                                  \
    av  = *(const float4*)(Ap + ko_);          /* 16B = 8 bf16 */              \
    bv0 = *(const float4*)(Bp + ko_); bv1 = *(const float4*)(Bp + ko_ + 4); }
#define WRITE2(t) { char* d_ = smem + ((t) & 3) * 16384;                       \
    *(float4*)(d_ + q * 16) = av;                                              \
    *(u16x8_t*)(d_ + 8192 + q * 16) = cvt8(bv0, bv1); }

    f32x4_t acc[4][2] = {};
    const int rsw = ((kg ^ ((lr >> 1) & 3)) * 16);
    const int arow = wr * 64 + lr;
    const int brow = wc * 32 + lr;

    LOADR2(0); WRITE2(0);
    LOADR2(1); WRITE2(1);
    LOADR2(2);
    __syncthreads();

    for (int t = 0; t < 32; ++t) {
        const int sb_ = (t & 3) * 16384;
        bf16x8_t a_[4], b_[2];
#pragma unroll
        for (int mi = 0; mi < 4; ++mi)
            a_[mi] = *(const bf16x8_t*)(smem + sb_ + (arow + mi * 16) * 64 + rsw);
#pragma unroll
        for (int ni = 0; ni < 2; ++ni)
            b_[ni] = *(const bf16x8_t*)(smem + sb_ + 8192 + (brow + ni * 16) * 64 + rsw);
        if (t < 30) WRITE2(t + 2);
        if (t < 29) LOADR2(t + 3);
        __builtin_amdgcn_s_setprio(1);
#pragma unroll
        for (int mi = 0; mi < 4; ++mi)
#pragma unroll
            for (int ni = 0; ni < 2; ++ni)
                acc[mi][ni] = __builtin_amdgcn_mfma_f32_16x16x32_bf16(
                    a_[mi], b_[ni], acc[mi][ni], 0, 0, 0);
        __builtin_amdgcn_s_setprio(0);
        __syncthreads();
    }
#undef LOADR2
#undef WRITE2

    // epilogue: 2 passes of 64 rows through [64][132] f32 LDS, fused bias
    float* cf = (float*)smem;
#pragma unroll
    for (int p = 0; p < 2; ++p) {
        if (p) __syncthreads();
        if (wr == p) {
#pragma unroll
            for (int mi = 0; mi < 4; ++mi)
#pragma unroll
                for (int ni = 0; ni < 2; ++ni) {
                    const int scol = wc * 32 + ni * 16 + lr;
#pragma unroll
                    for (int r = 0; r < 4; ++r)
                        cf[(mi * 16 + kg * 4 + r) * 132 + scol] = acc[mi][ni][r];
                }
        }
        __syncthreads();
#pragma unroll
        for (int cc = 0; cc < 4; ++cc) {
            const int chunk = tid + cc * 512;    // 2048 = 64 rows x 32 chunks
            const int srow = chunk >> 5;
            const int sc = (chunk & 31) * 4;
            f32x4_t v = *(const f32x4_t*)(smem + srow * 528 + sc * 4);
            const f32x4_t bv = *(const f32x4_t*)(bias + n0 + sc);
            v += bv;
            *(f32x4_t*)(C + (size_t)(m0 + p * 64 + srow) * Nn + n0 + sc) = v;
        }
    }
}

// ---------------- banded MFMA attention, block-shared K/V --------------------
__global__ __launch_bounds__(256) void attn_band_mfma(
    const __hip_bfloat16* __restrict__ qkv,
    __hip_bfloat16* __restrict__ ctx,
    const int* __restrict__ epoch_ptr)
{
    __shared__ __align__(16) __hip_bfloat16 K_lds[128 * 64];
    __shared__ __align__(16) __hip_bfloat16 V_lds[64 * 136];
    __shared__ __hip_bfloat16 P_lds[4][16 * 40];

    const int tid = threadIdx.x;
    const int wave = tid >> 6, lane = tid & 63;
    const int lr = lane & 15, kg = lane >> 4;

    const int bid = blockIdx.x;
    const int tg = bid & 15;
    const int bh = bid >> 4;
    const int h = bh & 15, b = bh >> 4;
    const int base = tg * 64;
    const int i0 = base + wave * 16;

    const int e = *epoch_ptr;
    int w;
    if      (e < 20) w = 6;
    else if (e < 30) w = 8;
    else if (e < 40) w = 10;
    else if (e < 50) w = 12;
    else             w = 1023;

    const size_t rowb = (size_t)b * 1024;
    const int hq = h * 192;

#pragma unroll
    for (int it = 0; it < 4; ++it) {
        const int q = tid + it * 256;
        const int row = q >> 3, s = q & 7;
        const int c = s ^ (row & 7);
        int gk = base - 32 + row;
        gk = gk < 0 ? 0 : (gk > 1023 ? 1023 : gk);
        load_lds16(qkv + (rowb + gk) * 3072 + hq + 64 + c * 8,
                   (char*)K_lds + q * 16);
    }
    {
        const int pr = tid & 63, dg = tid >> 6;
        int gk0 = base - 32 + 2 * pr, gk1 = gk0 + 1;
        gk0 = gk0 < 0 ? 0 : (gk0 > 1023 ? 1023 : gk0);
        gk1 = gk1 < 0 ? 0 : (gk1 > 1023 ? 1023 : gk1);
        const __hip_bfloat16* v0 = qkv + (rowb + gk0) * 3072 + hq + 128 + dg * 16;
        const __hip_bfloat16* v1 = qkv + (rowb + gk1) * 3072 + hq + 128 + dg * 16;
        u16x8_t a0 = *(const u16x8_t*)v0, b0 = *(const u16x8_t*)(v0 + 8);
        u16x8_t a1 = *(const u16x8_t*)v1, b1 = *(const u16x8_t*)(v1 + 8);
#pragma unroll
        for (int c2 = 0; c2 < 8; ++c2) {
            *(unsigned int*)&V_lds[(dg * 16 + c2) * 136 + 2 * pr] =
                (unsigned int)a0[c2] | ((unsigned int)a1[c2] << 16);
            *(unsigned int*)&V_lds[(dg * 16 + 8 + c2) * 136 + 2 * pr] =
                (unsigned int)b0[c2] | ((unsigned int)b1[c2] << 16);
        }
    }

    bf16x8_t aq[2];
#pragma unroll
    for (int ks = 0; ks < 2; ++ks)
        aq[ks] = *(const bf16x8_t*)(qkv + (rowb + i0 + lr) * 3072 + hq + ks * 32 + kg * 8);

    __syncthreads();

    float m[4] = {-1e30f, -1e30f, -1e30f, -1e30f};
    float l[4] = {0.f, 0.f, 0.f, 0.f};
    f32x4_t o[4] = {};

    int jlo = i0 - w;      if (jlo < 0) jlo = 0;
    int jhi = i0 + 15 + w; if (jhi > 1023) jhi = 1023;
    const int t0 = (base >> 5) - 1;

    for (int p = (jlo >> 5); p <= (jhi >> 5); ++p) {
        const int kb = p * 32;
        const int tl = p - t0;

        f32x4_t s2[2] = {};
#pragma unroll
        for (int t = 0; t < 2; ++t)
#pragma unroll
            for (int ks = 0; ks < 2; ++ks) {
                const int lkr = tl * 32 + t * 16 + lr;
                bf16x8_t bk = *(const bf16x8_t*)(
                    (char*)K_lds + lkr * 128 + (((ks * 4 + kg) ^ (lr & 7)) * 16));
                s2[t] = __builtin_amdgcn_mfma_f32_16x16x32_bf16(aq[ks], bk, s2[t], 0, 0, 0);
            }

        float sv[2][4];
#pragma unroll
        for (int t = 0; t < 2; ++t)
#pragma unroll
            for (int r = 0; r < 4; ++r) {
                const int qi = i0 + kg * 4 + r;
                const int j  = kb + t * 16 + lr;
                int d = qi - j; if (d < 0) d = -d;
                sv[t][r] = (d <= w) ? s2[t][r] * 0.125f : -1e30f;
            }

        float tm[4];
#pragma unroll
        for (int r = 0; r < 4; ++r) tm[r] = fmaxf(sv[0][r], sv[1][r]);
#pragma unroll
        for (int msk = 1; msk < 16; msk <<= 1)
#pragma unroll
            for (int r = 0; r < 4; ++r) tm[r] = fmaxf(tm[r], __shfl_xor(tm[r], msk));

        float sc[4], ps[4], pvv[2][4];
#pragma unroll
        for (int r = 0; r < 4; ++r) {
            const float mn = fmaxf(m[r], tm[r]);
            sc[r] = __expf(m[r] - mn);
            pvv[0][r] = __expf(sv[0][r] - mn);
            pvv[1][r] = __expf(sv[1][r] - mn);
            ps[r] = pvv[0][r] + pvv[1][r];
            m[r] = mn;
        }
#pragma unroll
        for (int msk = 1; msk < 16; msk <<= 1)
#pragma unroll
            for (int r = 0; r < 4; ++r) ps[r] += __shfl_xor(ps[r], msk);
#pragma unroll
        for (int r = 0; r < 4; ++r) l[r] = l[r] * sc[r] + ps[r];
#pragma unroll
        for (int ni = 0; ni < 4; ++ni)
#pragma unroll
            for (int r = 0; r < 4; ++r) o[ni][r] *= sc[r];

#pragma unroll
        for (int t = 0; t < 2; ++t)
#pragma unroll
            for (int r = 0; r < 4; ++r)
                P_lds[wave][(kg * 4 + r) * 40 + t * 16 + lr] =
                    __float2bfloat16(pvv[t][r]);

        bf16x8_t ap = *(const bf16x8_t*)&P_lds[wave][lr * 40 + kg * 8];
#pragma unroll
        for (int ni = 0; ni < 4; ++ni) {
            bf16x8_t bv = *(const bf16x8_t*)&V_lds[(ni * 16 + lr) * 136 + tl * 32 + kg * 8];
            o[ni] = __builtin_amdgcn_mfma_f32_16x16x32_bf16(ap, bv, o[ni], 0, 0, 0);
        }
    }

#pragma unroll
    for (int ni = 0; ni < 4; ++ni)
#pragma unroll
        for (int r = 0; r < 4; ++r)
            ctx[(rowb + i0 + kg * 4 + r) * 1024 + h * 64 + ni * 16 + lr] =
                __float2bfloat16(o[ni][r] / l[r]);
}

// ---------------- launch -----------------------------------------------------
extern "C" void kernel_launch(void* const* d_in, const int* in_sizes, int n_in,
                              void* d_out, int out_size, void* d_ws, size_t ws_size,
                              hipStream_t stream)
{
    const float* x     = (const float*)d_in[0];
    const float* Wqkv  = (const float*)d_in[1];
    const float* Wproj = (const float*)d_in[2];
    const float* bproj = (const float*)d_in[3];
    const int*   epoch = (const int*)d_in[4];

    char* ws = (char*)d_ws;
    __hip_bfloat16* qkvb = (__hip_bfloat16*)(ws);              // 25165824 B
    __hip_bfloat16* ctxb = (__hip_bfloat16*)(ws + 25165824);   // 8388608 B

    gemm1_qkv<<<dim3(16, 16), 512, 0, stream>>>(x, Wqkv, qkvb);

    attn_band_mfma<<<1024, 256, 0, stream>>>(qkvb, ctxb, epoch);

    gemm2_proj<<<dim3(8, 32), 512, 0, stream>>>(
        ctxb, Wproj, (float*)d_out, bproj);
}